// Round 1
// baseline (322.449 us; speedup 1.0000x reference)
//
#include <hip/hip_runtime.h>
#include <stdint.h>

typedef __attribute__((ext_vector_type(4))) float f32x4;
typedef __attribute__((ext_vector_type(8))) short short8;
typedef unsigned short u16;
typedef unsigned int u32;
typedef unsigned long long u64;

#define GLDS16(g, l) __builtin_amdgcn_global_load_lds( \
    (const __attribute__((address_space(1))) void*)(g), \
    (__attribute__((address_space(3))) void*)(l), 16, 0, 0)

__device__ __forceinline__ u16 f2bf(float x) {
  u32 u = __float_as_uint(x);
  u += 0x7fffu + ((u >> 16) & 1u);
  return (u16)(u >> 16);
}

// ---------- prep: fp32->bf16 conversions + mask bit-pack ----------
__global__ __launch_bounds__(256) void prep_kernel(
    const float* __restrict__ q, const float* __restrict__ k,
    const float* __restrict__ v, const int* __restrict__ mask,
    const float* __restrict__ Wq, const float* __restrict__ Wk,
    const float* __restrict__ Wv, const float* __restrict__ Wo,
    u16* __restrict__ X, u16* __restrict__ Wb, u64* __restrict__ mb)
{
  const size_t tid = (size_t)blockIdx.x * 256 + threadIdx.x;
  const size_t nth = (size_t)gridDim.x * 256;
  // q,k,v -> X : 3 x 4194304 bf16, 8 floats/iter
  for (size_t i = tid; i < 3ull * 524288ull; i += nth) {
    const int a = (int)(i / 524288ull);
    const size_t j = i - (size_t)a * 524288ull;
    const float4* s4 = (const float4*)(a == 0 ? q : a == 1 ? k : v);
    float4 x = s4[2 * j], y = s4[2 * j + 1];
    uint4 o;
    o.x = (u32)f2bf(x.x) | ((u32)f2bf(x.y) << 16);
    o.y = (u32)f2bf(x.z) | ((u32)f2bf(x.w) << 16);
    o.z = (u32)f2bf(y.x) | ((u32)f2bf(y.y) << 16);
    o.w = (u32)f2bf(y.z) | ((u32)f2bf(y.w) << 16);
    ((uint4*)X)[i] = o;
  }
  // Wq,Wk,Wv,Wo -> Wb : 4 x 1048576 bf16
  for (size_t i = tid; i < 4ull * 131072ull; i += nth) {
    const int a = (int)(i / 131072ull);
    const size_t j = i - (size_t)a * 131072ull;
    const float4* s4 = (const float4*)(a == 0 ? Wq : a == 1 ? Wk : a == 2 ? Wv : Wo);
    float4 x = s4[2 * j], y = s4[2 * j + 1];
    uint4 o;
    o.x = (u32)f2bf(x.x) | ((u32)f2bf(x.y) << 16);
    o.y = (u32)f2bf(x.z) | ((u32)f2bf(x.w) << 16);
    o.z = (u32)f2bf(y.x) | ((u32)f2bf(y.y) << 16);
    o.w = (u32)f2bf(y.z) | ((u32)f2bf(y.w) << 16);
    ((uint4*)Wb)[i] = o;
  }
  // mask (int32, nonzero = masked) -> 1 bit
  const int lane = threadIdx.x & 63;
  const size_t wid = tid >> 6, nw = nth >> 6;
  for (size_t wi = wid; wi < 131072ull; wi += nw) {
    int mm = mask[wi * 64 + lane];
    u64 bal = __ballot(mm != 0);
    if (lane == 0) mb[wi] = bal;
  }
}

// ---------- QKV projection GEMM: 128x128 tile, BK=64, NT bf16 ----------
__global__ __launch_bounds__(256, 2) void gemm_qkv_kernel(
    const u16* __restrict__ X, const u16* __restrict__ W,
    const float* __restrict__ bq, const float* __restrict__ bk,
    const float* __restrict__ bv,
    u16* __restrict__ Qb, u16* __restrict__ Kb, u16* __restrict__ Vt)
{
  const int z = blockIdx.z;
  const char* A = (const char*)(X + (size_t)z * 4194304ull);
  const char* B = (const char*)(W + (size_t)z * 1048576ull);
  const float* bias = (z == 0) ? bq : (z == 1) ? bk : bv;
  const int m0 = blockIdx.y * 128, n0 = blockIdx.x * 128;
  const int tid = threadIdx.x, l = tid & 63, w = tid >> 6;
  const int wm = w >> 1, wn = w & 1;
  __shared__ __attribute__((aligned(16))) char Asm[16384];
  __shared__ __attribute__((aligned(16))) char Bsm[16384];
  f32x4 acc[4][4] = {};
  for (int kt = 0; kt < 16; ++kt) {
#pragma unroll
    for (int j = 0; j < 4; ++j) {
      const int rt = w * 32 + j * 8 + (l >> 3);
      const int swk = ((l & 7) * 16) ^ ((rt & 7) << 4);
      GLDS16(A + (size_t)(m0 + rt) * 2048 + kt * 128 + swk, Asm + (w * 32 + j * 8) * 128);
      GLDS16(B + (size_t)(n0 + rt) * 2048 + kt * 128 + swk, Bsm + (w * 32 + j * 8) * 128);
    }
    __syncthreads();
#pragma unroll
    for (int kk = 0; kk < 2; ++kk) {
      short8 af[4], bfr[4];
#pragma unroll
      for (int mf = 0; mf < 4; ++mf) {
        const int row = wm * 64 + mf * 16 + (l & 15);
        const int kb = kk * 64 + (l >> 4) * 16;
        af[mf] = *(const short8*)(Asm + row * 128 + (kb ^ ((row & 7) << 4)));
      }
#pragma unroll
      for (int fc = 0; fc < 4; ++fc) {
        const int row = wn * 64 + fc * 16 + (l & 15);
        const int kb = kk * 64 + (l >> 4) * 16;
        bfr[fc] = *(const short8*)(Bsm + row * 128 + (kb ^ ((row & 7) << 4)));
      }
#pragma unroll
      for (int mf = 0; mf < 4; ++mf)
#pragma unroll
        for (int fc = 0; fc < 4; ++fc)
          acc[mf][fc] = __builtin_amdgcn_mfma_f32_16x16x32_bf16(af[mf], bfr[fc], acc[mf][fc], 0, 0, 0);
    }
    __syncthreads();
  }
  const float scale = (z == 0) ? 0.125f : 1.0f;  // fold 1/sqrt(64) into Q
#pragma unroll
  for (int mf = 0; mf < 4; ++mf) {
#pragma unroll
    for (int fc = 0; fc < 4; ++fc) {
#pragma unroll
      for (int r = 0; r < 4; ++r) {
        const int m = m0 + wm * 64 + mf * 16 + (l >> 4) * 4 + r;
        const int n = n0 + wn * 64 + fc * 16 + (l & 15);
        const float val = (acc[mf][fc][r] + bias[n]) * scale;
        const u16 b16 = f2bf(val);
        const int bb = m >> 11, s = m & 2047;
        const int h = n >> 6, dd = n & 63;
        const int bh = bb * 16 + h;
        if (z < 2) {
          u16* dst = (z == 0) ? Qb : Kb;
          dst[((size_t)bh * 2048 + s) * 64 + dd] = b16;       // [bh][s][d]
        } else {
          Vt[((size_t)bh * 64 + dd) * 2048 + s] = b16;        // [bh][d][s] (pre-transposed)
        }
      }
    }
  }
}

// ---------- fused attention: stats pass + (attn write + PV) pass ----------
__global__ __launch_bounds__(256, 2) void attn_sp_kernel(
    const u16* __restrict__ Qb, const u16* __restrict__ Kb,
    const u16* __restrict__ Vt, const u32* __restrict__ mbits,
    float* __restrict__ attn, u16* __restrict__ preWo)
{
  const int bh = blockIdx.y, qb = blockIdx.x;
  const int b = bh >> 4, h = bh & 15;
  const int q0 = qb * 128;
  const int tid = threadIdx.x, l = tid & 63, w = tid >> 6;
  __shared__ __attribute__((aligned(16))) char QVsm[16384];  // Q tile, reused for V tiles
  __shared__ __attribute__((aligned(16))) char Ksm[16384];
  __shared__ __attribute__((aligned(16))) char Psm[32768];

  const char* Qrow = (const char*)(Qb + (size_t)bh * 131072ull);
  const char* Krow = (const char*)(Kb + (size_t)bh * 131072ull);
  const char* Vrow = (const char*)(Vt + (size_t)bh * 131072ull);

  // stage Q tile (swizzled source -> linear LDS; swizzle applied on reads)
#pragma unroll
  for (int j = 0; j < 4; ++j) {
    const int rt = w * 32 + j * 8 + (l >> 3);
    const int swk = ((l & 7) * 16) ^ ((rt & 7) << 4);
    GLDS16(Qrow + (size_t)(q0 + rt) * 128 + swk, QVsm + (w * 32 + j * 8) * 128);
  }
  __syncthreads();
  short8 aq[2][2];
#pragma unroll
  for (int mf = 0; mf < 2; ++mf)
#pragma unroll
    for (int kk = 0; kk < 2; ++kk) {
      const int row = w * 32 + mf * 16 + (l & 15);
      const int kb = kk * 64 + (l >> 4) * 16;
      aq[mf][kk] = *(const short8*)(QVsm + row * 128 + (kb ^ ((row & 7) << 4)));
    }
  __syncthreads();

  float mrun[2][4], lrun[2][4];
#pragma unroll
  for (int mf = 0; mf < 2; ++mf)
#pragma unroll
    for (int r = 0; r < 4; ++r) { mrun[mf][r] = -1e30f; lrun[mf][r] = 0.f; }

  // ---- pass 1: row max / sum-exp ----
  for (int kt = 0; kt < 16; ++kt) {
#pragma unroll
    for (int j = 0; j < 4; ++j) {
      const int rt = w * 32 + j * 8 + (l >> 3);
      const int swk = ((l & 7) * 16) ^ ((rt & 7) << 4);
      GLDS16(Krow + (size_t)(kt * 128 + rt) * 128 + swk, Ksm + (w * 32 + j * 8) * 128);
    }
    __syncthreads();
    f32x4 sc[2][8] = {};
#pragma unroll
    for (int kk = 0; kk < 2; ++kk) {
      short8 bkf[8];
#pragma unroll
      for (int fc = 0; fc < 8; ++fc) {
        const int row = fc * 16 + (l & 15);
        const int kb = kk * 64 + (l >> 4) * 16;
        bkf[fc] = *(const short8*)(Ksm + row * 128 + (kb ^ ((row & 7) << 4)));
      }
#pragma unroll
      for (int mf = 0; mf < 2; ++mf)
#pragma unroll
        for (int fc = 0; fc < 8; ++fc)
          sc[mf][fc] = __builtin_amdgcn_mfma_f32_16x16x32_bf16(aq[mf][kk], bkf[fc], sc[mf][fc], 0, 0, 0);
    }
#pragma unroll
    for (int mf = 0; mf < 2; ++mf) {
#pragma unroll
      for (int r = 0; r < 4; ++r) {
        const int qg = q0 + w * 32 + mf * 16 + (l >> 4) * 4 + r;
        const uint4 mk = *(const uint4*)(mbits + ((size_t)(b * 2048 + qg) * 64 + kt * 4));
        float vals[8];
        float rmax = -1e30f;
#pragma unroll
        for (int fc = 0; fc < 8; ++fc) {
          float sv = sc[mf][fc][r];
          const u32 mw = (fc < 2) ? mk.x : (fc < 4) ? mk.y : (fc < 6) ? mk.z : mk.w;
          const int sh = (l & 15) + ((fc & 1) << 4);
          if ((mw >> sh) & 1u) sv = -1e30f;
          vals[fc] = sv;
          rmax = fmaxf(rmax, sv);
        }
#pragma unroll
        for (int d = 1; d < 16; d <<= 1) rmax = fmaxf(rmax, __shfl_xor(rmax, d));
        const float nm = fmaxf(mrun[mf][r], rmax);
        float se = 0.f;
#pragma unroll
        for (int fc = 0; fc < 8; ++fc) se += __expf(vals[fc] - nm);
#pragma unroll
        for (int d = 1; d < 16; d <<= 1) se += __shfl_xor(se, d);
        lrun[mf][r] = lrun[mf][r] * __expf(mrun[mf][r] - nm) + se;
        mrun[mf][r] = nm;
      }
    }
    __syncthreads();
  }

  float il[2][4];
#pragma unroll
  for (int mf = 0; mf < 2; ++mf)
#pragma unroll
    for (int r = 0; r < 4; ++r) il[mf][r] = 1.0f / lrun[mf][r];

  f32x4 oacc[2][4] = {};

  // ---- pass 2: attn write + PV ----
  for (int kt = 0; kt < 16; ++kt) {
#pragma unroll
    for (int j = 0; j < 4; ++j) {
      const int rt = w * 32 + j * 8 + (l >> 3);
      const int swk = ((l & 7) * 16) ^ ((rt & 7) << 4);
      GLDS16(Krow + (size_t)(kt * 128 + rt) * 128 + swk, Ksm + (w * 32 + j * 8) * 128);
    }
#pragma unroll
    for (int j = 0; j < 4; ++j) {
      const int rt = w * 16 + j * 4 + (l >> 4);
      const int swk = ((l & 15) * 16) ^ ((rt & 7) << 4);
      GLDS16(Vrow + (size_t)rt * 4096 + kt * 256 + swk, QVsm + (w * 16 + j * 4) * 256);
    }
    __syncthreads();
    f32x4 sc[2][8] = {};
#pragma unroll
    for (int kk = 0; kk < 2; ++kk) {
      short8 bkf[8];
#pragma unroll
      for (int fc = 0; fc < 8; ++fc) {
        const int row = fc * 16 + (l & 15);
        const int kb = kk * 64 + (l >> 4) * 16;
        bkf[fc] = *(const short8*)(Ksm + row * 128 + (kb ^ ((row & 7) << 4)));
      }
#pragma unroll
      for (int mf = 0; mf < 2; ++mf)
#pragma unroll
        for (int fc = 0; fc < 8; ++fc)
          sc[mf][fc] = __builtin_amdgcn_mfma_f32_16x16x32_bf16(aq[mf][kk], bkf[fc], sc[mf][fc], 0, 0, 0);
    }
#pragma unroll
    for (int mf = 0; mf < 2; ++mf) {
#pragma unroll
      for (int r = 0; r < 4; ++r) {
        const int qg = q0 + w * 32 + mf * 16 + (l >> 4) * 4 + r;
        const uint4 mk = *(const uint4*)(mbits + ((size_t)(b * 2048 + qg) * 64 + kt * 4));
        float* arow = attn + ((size_t)bh * 2048 + qg) * 2048 + kt * 128;
        const int qlocal = w * 32 + mf * 16 + (l >> 4) * 4 + r;
#pragma unroll
        for (int fc = 0; fc < 8; ++fc) {
          float sv = sc[mf][fc][r];
          const u32 mw = (fc < 2) ? mk.x : (fc < 4) ? mk.y : (fc < 6) ? mk.z : mk.w;
          const int sh = (l & 15) + ((fc & 1) << 4);
          if ((mw >> sh) & 1u) sv = -1e30f;
          const float p = __expf(sv - mrun[mf][r]) * il[mf][r];
          __builtin_nontemporal_store(p, arow + fc * 16 + (l & 15));
          const int cb = (fc * 16 + (l & 15)) * 2;
          *(u16*)(Psm + qlocal * 256 + (cb ^ ((qlocal & 7) << 4))) = f2bf(p);
        }
      }
    }
    // PV (per-wave private Psm region: no barrier needed between write and read)
#pragma unroll
    for (int kk = 0; kk < 4; ++kk) {
      short8 pa[2], vb[4];
#pragma unroll
      for (int mf = 0; mf < 2; ++mf) {
        const int row = w * 32 + mf * 16 + (l & 15);
        const int kb = kk * 64 + (l >> 4) * 16;
        pa[mf] = *(const short8*)(Psm + row * 256 + (kb ^ ((row & 7) << 4)));
      }
#pragma unroll
      for (int fn = 0; fn < 4; ++fn) {
        const int row = fn * 16 + (l & 15);
        const int kb = kk * 64 + (l >> 4) * 16;
        vb[fn] = *(const short8*)(QVsm + row * 256 + (kb ^ ((row & 7) << 4)));
      }
#pragma unroll
      for (int mf = 0; mf < 2; ++mf)
#pragma unroll
        for (int fn = 0; fn < 4; ++fn)
          oacc[mf][fn] = __builtin_amdgcn_mfma_f32_16x16x32_bf16(pa[mf], vb[fn], oacc[mf][fn], 0, 0, 0);
    }
    __syncthreads();
  }

  // epilogue: scatter O into the reference's buggy-reshape layout (bf16)
#pragma unroll
  for (int mf = 0; mf < 2; ++mf)
#pragma unroll
    for (int fn = 0; fn < 4; ++fn)
#pragma unroll
      for (int r = 0; r < 4; ++r) {
        const int sg = q0 + w * 32 + mf * 16 + (l >> 4) * 4 + r;
        const int dd = fn * 16 + (l & 15);
        const size_t off = (size_t)b * 2097152ull +
                           ((size_t)((h >> 1) * 256 + (sg >> 3))) * 1024ull +
                           (size_t)((sg & 7) * 128 + (h & 1) * 64 + dd);
        preWo[off] = f2bf(oacc[mf][fn][r]);
      }
}

// ---------- output projection GEMM ----------
__global__ __launch_bounds__(256, 2) void gemm_out_kernel(
    const u16* __restrict__ A0, const u16* __restrict__ B0,
    const float* __restrict__ bias, float* __restrict__ out)
{
  const char* A = (const char*)A0;
  const char* B = (const char*)B0;
  const int m0 = blockIdx.y * 128, n0 = blockIdx.x * 128;
  const int tid = threadIdx.x, l = tid & 63, w = tid >> 6;
  const int wm = w >> 1, wn = w & 1;
  __shared__ __attribute__((aligned(16))) char Asm[16384];
  __shared__ __attribute__((aligned(16))) char Bsm[16384];
  f32x4 acc[4][4] = {};
  for (int kt = 0; kt < 16; ++kt) {
#pragma unroll
    for (int j = 0; j < 4; ++j) {
      const int rt = w * 32 + j * 8 + (l >> 3);
      const int swk = ((l & 7) * 16) ^ ((rt & 7) << 4);
      GLDS16(A + (size_t)(m0 + rt) * 2048 + kt * 128 + swk, Asm + (w * 32 + j * 8) * 128);
      GLDS16(B + (size_t)(n0 + rt) * 2048 + kt * 128 + swk, Bsm + (w * 32 + j * 8) * 128);
    }
    __syncthreads();
#pragma unroll
    for (int kk = 0; kk < 2; ++kk) {
      short8 af[4], bfr[4];
#pragma unroll
      for (int mf = 0; mf < 4; ++mf) {
        const int row = wm * 64 + mf * 16 + (l & 15);
        const int kb = kk * 64 + (l >> 4) * 16;
        af[mf] = *(const short8*)(Asm + row * 128 + (kb ^ ((row & 7) << 4)));
      }
#pragma unroll
      for (int fc = 0; fc < 4; ++fc) {
        const int row = wn * 64 + fc * 16 + (l & 15);
        const int kb = kk * 64 + (l >> 4) * 16;
        bfr[fc] = *(const short8*)(Bsm + row * 128 + (kb ^ ((row & 7) << 4)));
      }
#pragma unroll
      for (int mf = 0; mf < 4; ++mf)
#pragma unroll
        for (int fc = 0; fc < 4; ++fc)
          acc[mf][fc] = __builtin_amdgcn_mfma_f32_16x16x32_bf16(af[mf], bfr[fc], acc[mf][fc], 0, 0, 0);
    }
    __syncthreads();
  }
#pragma unroll
  for (int mf = 0; mf < 4; ++mf)
#pragma unroll
    for (int fc = 0; fc < 4; ++fc)
#pragma unroll
      for (int r = 0; r < 4; ++r) {
        const int m = m0 + wm * 64 + mf * 16 + (l >> 4) * 4 + r;
        const int n = n0 + wn * 64 + fc * 16 + (l & 15);
        out[(size_t)m * 1024 + n] = acc[mf][fc][r] + bias[n];
      }
}

extern "C" void kernel_launch(void* const* d_in, const int* in_sizes, int n_in,
                              void* d_out, int out_size, void* d_ws, size_t ws_size,
                              hipStream_t stream) {
  const float* q  = (const float*)d_in[0];
  const float* k  = (const float*)d_in[1];
  const float* v  = (const float*)d_in[2];
  const int*  mask = (const int*)d_in[3];
  // d_in[4] = num_heads (fixed 16)
  const float* Wq = (const float*)d_in[5];
  const float* bq = (const float*)d_in[6];
  const float* Wk = (const float*)d_in[7];
  const float* bk = (const float*)d_in[8];
  const float* Wv = (const float*)d_in[9];
  const float* bv = (const float*)d_in[10];
  const float* Wo = (const float*)d_in[11];
  const float* bo = (const float*)d_in[12];

  float* out0 = (float*)d_out;
  float* attn = out0 + 4194304;            // [32][2048][2048] fp32
  u16* X = (u16*)attn;                     // bf16 q,k,v copies live in the attn
                                           // region until attn_sp overwrites it
  char* ws = (char*)d_ws;
  u16* Qb    = (u16*)(ws);                 // [32][2048][64] bf16
  u16* Kb    = (u16*)(ws + 8388608);
  u16* Vt    = (u16*)(ws + 16777216);      // [32][64][2048] bf16
  u16* preWo = (u16*)(ws + 25165824);      // [4096][1024] bf16 (scrambled layout)
  u16* Wb    = (u16*)(ws + 33554432);      // Wq,Wk,Wv,Wo bf16
  u32* mbits = (u32*)(ws + 41943040);      // [2][2048][64] bit-packed mask

  prep_kernel<<<dim3(1024), 256, 0, stream>>>(q, k, v, mask, Wq, Wk, Wv, Wo,
                                              X, Wb, (u64*)mbits);
  gemm_qkv_kernel<<<dim3(8, 32, 3), 256, 0, stream>>>(X, Wb, bq, bk, bv, Qb, Kb, Vt);
  attn_sp_kernel<<<dim3(16, 32), 256, 0, stream>>>(Qb, Kb, Vt, mbits, attn, preWo);
  gemm_out_kernel<<<dim3(8, 32), 256, 0, stream>>>(preWo, Wb + 3u * 1048576u, bo, out0);
}

// Round 2
// 299.950 us; speedup vs baseline: 1.0750x; 1.0750x over previous
//
#include <hip/hip_runtime.h>
#include <stdint.h>

typedef __attribute__((ext_vector_type(4))) float f32x4;
typedef __attribute__((ext_vector_type(8))) short short8;
typedef unsigned short u16;
typedef unsigned int u32;
typedef unsigned long long u64;

#define GLDS16(g, l) __builtin_amdgcn_global_load_lds( \
    (const __attribute__((address_space(1))) void*)(g), \
    (__attribute__((address_space(3))) void*)(l), 16, 0, 0)

#if __has_builtin(__builtin_amdgcn_exp2f)
#define EXP2(x) __builtin_amdgcn_exp2f(x)
#else
#define EXP2(x) __expf(0.69314718056f * (x))
#endif

__device__ __forceinline__ u16 f2bf(float x) {
  u32 u = __float_as_uint(x);
  u += 0x7fffu + ((u >> 16) & 1u);
  return (u16)(u >> 16);
}

// ---------- prep: fp32->bf16 conversions + mask bit-pack ----------
__global__ __launch_bounds__(256) void prep_kernel(
    const float* __restrict__ q, const float* __restrict__ k,
    const float* __restrict__ v, const int* __restrict__ mask,
    const float* __restrict__ Wq, const float* __restrict__ Wk,
    const float* __restrict__ Wv, const float* __restrict__ Wo,
    u16* __restrict__ X, u16* __restrict__ Wb, u64* __restrict__ mb)
{
  const size_t tid = (size_t)blockIdx.x * 256 + threadIdx.x;
  const size_t nth = (size_t)gridDim.x * 256;
  for (size_t i = tid; i < 3ull * 524288ull; i += nth) {
    const int a = (int)(i / 524288ull);
    const size_t j = i - (size_t)a * 524288ull;
    const float4* s4 = (const float4*)(a == 0 ? q : a == 1 ? k : v);
    float4 x = s4[2 * j], y = s4[2 * j + 1];
    uint4 o;
    o.x = (u32)f2bf(x.x) | ((u32)f2bf(x.y) << 16);
    o.y = (u32)f2bf(x.z) | ((u32)f2bf(x.w) << 16);
    o.z = (u32)f2bf(y.x) | ((u32)f2bf(y.y) << 16);
    o.w = (u32)f2bf(y.z) | ((u32)f2bf(y.w) << 16);
    ((uint4*)X)[i] = o;
  }
  for (size_t i = tid; i < 4ull * 131072ull; i += nth) {
    const int a = (int)(i / 131072ull);
    const size_t j = i - (size_t)a * 131072ull;
    const float4* s4 = (const float4*)(a == 0 ? Wq : a == 1 ? Wk : a == 2 ? Wv : Wo);
    float4 x = s4[2 * j], y = s4[2 * j + 1];
    uint4 o;
    o.x = (u32)f2bf(x.x) | ((u32)f2bf(x.y) << 16);
    o.y = (u32)f2bf(x.z) | ((u32)f2bf(x.w) << 16);
    o.z = (u32)f2bf(y.x) | ((u32)f2bf(y.y) << 16);
    o.w = (u32)f2bf(y.z) | ((u32)f2bf(y.w) << 16);
    ((uint4*)Wb)[i] = o;
  }
  const int lane = threadIdx.x & 63;
  const size_t wid = tid >> 6, nw = nth >> 6;
  for (size_t wi = wid; wi < 131072ull; wi += nw) {
    int mm = mask[wi * 64 + lane];
    u64 bal = __ballot(mm != 0);
    if (lane == 0) mb[wi] = bal;
  }
}

// ---------- QKV projection GEMM: 128x128 tile, BK=64, NT bf16 ----------
__global__ __launch_bounds__(256, 2) void gemm_qkv_kernel(
    const u16* __restrict__ X, const u16* __restrict__ W,
    const float* __restrict__ bq, const float* __restrict__ bk,
    const float* __restrict__ bv,
    u16* __restrict__ Qb, u16* __restrict__ Kb, u16* __restrict__ Vt)
{
  const int z = blockIdx.z;
  const char* A = (const char*)(X + (size_t)z * 4194304ull);
  const char* B = (const char*)(W + (size_t)z * 1048576ull);
  const float* bias = (z == 0) ? bq : (z == 1) ? bk : bv;
  const int m0 = blockIdx.y * 128, n0 = blockIdx.x * 128;
  const int tid = threadIdx.x, l = tid & 63, w = tid >> 6;
  const int wm = w >> 1, wn = w & 1;
  __shared__ __attribute__((aligned(16))) char SM[32768];
  char* Asm = SM;
  char* Bsm = SM + 16384;
  f32x4 acc[4][4] = {};
  for (int kt = 0; kt < 16; ++kt) {
#pragma unroll
    for (int j = 0; j < 4; ++j) {
      const int rt = w * 32 + j * 8 + (l >> 3);
      const int swk = ((l & 7) * 16) ^ ((rt & 7) << 4);
      GLDS16(A + (size_t)(m0 + rt) * 2048 + kt * 128 + swk, Asm + (w * 32 + j * 8) * 128);
      GLDS16(B + (size_t)(n0 + rt) * 2048 + kt * 128 + swk, Bsm + (w * 32 + j * 8) * 128);
    }
    __syncthreads();
#pragma unroll
    for (int kk = 0; kk < 2; ++kk) {
      short8 af[4], bfr[4];
#pragma unroll
      for (int mf = 0; mf < 4; ++mf) {
        const int row = wm * 64 + mf * 16 + (l & 15);
        const int kb = kk * 64 + (l >> 4) * 16;
        af[mf] = *(const short8*)(Asm + row * 128 + (kb ^ ((row & 7) << 4)));
      }
#pragma unroll
      for (int fc = 0; fc < 4; ++fc) {
        const int row = wn * 64 + fc * 16 + (l & 15);
        const int kb = kk * 64 + (l >> 4) * 16;
        bfr[fc] = *(const short8*)(Bsm + row * 128 + (kb ^ ((row & 7) << 4)));
      }
#pragma unroll
      for (int mf = 0; mf < 4; ++mf)
#pragma unroll
        for (int fc = 0; fc < 4; ++fc)
          acc[mf][fc] = __builtin_amdgcn_mfma_f32_16x16x32_bf16(af[mf], bfr[fc], acc[mf][fc], 0, 0, 0);
    }
    __syncthreads();
  }
  if (z < 2) {
    // fold 1/sqrt(64) * log2(e) into Q (attention runs in exp2 domain)
    const float scale = (z == 0) ? 0.18033688011f : 1.0f;
    u16* dst = (z == 0) ? Qb : Kb;
#pragma unroll
    for (int mf = 0; mf < 4; ++mf)
#pragma unroll
      for (int fc = 0; fc < 4; ++fc)
#pragma unroll
        for (int r = 0; r < 4; ++r) {
          const int m = m0 + wm * 64 + mf * 16 + (l >> 4) * 4 + r;
          const int n = n0 + wn * 64 + fc * 16 + (l & 15);
          const float val = (acc[mf][fc][r] + bias[n]) * scale;
          const int bb = m >> 11, s = m & 2047;
          const int hh = n >> 6, dd = n & 63;
          dst[((size_t)(bb * 16 + hh) * 2048 + s) * 64 + dd] = f2bf(val);
        }
  } else {
    // transpose tile through LDS for coalesced Vt ([bh][d][s]) stores
#pragma unroll
    for (int mf = 0; mf < 4; ++mf)
#pragma unroll
      for (int fc = 0; fc < 4; ++fc)
#pragma unroll
        for (int r = 0; r < 4; ++r) {
          const int n_l = wn * 64 + fc * 16 + (l & 15);
          const int m_l = wm * 64 + mf * 16 + (l >> 4) * 4 + r;
          const float val = acc[mf][fc][r] + bias[n0 + n_l];
          *(u16*)(SM + n_l * 256 + ((m_l * 2) ^ ((n_l & 15) << 4))) = f2bf(val);
        }
    __syncthreads();
    const int bb = m0 >> 11, ms = m0 & 2047;
#pragma unroll
    for (int rep = 0; rep < 8; ++rep) {
      const int n_l = rep * 16 + (tid >> 4);
      const int m8 = (tid & 15) * 8;
      const uint4 dv = *(const uint4*)(SM + n_l * 256 + ((m8 * 2) ^ ((n_l & 15) << 4)));
      const int hh = (n0 + n_l) >> 6, dd = (n0 + n_l) & 63;
      *(uint4*)(Vt + ((size_t)((bb * 16 + hh) * 64 + dd)) * 2048 + ms + m8) = dv;
    }
  }
}

// ---------- fused attention: stats pass + (attn write + PV) pass ----------
__global__ __launch_bounds__(256, 2) void attn_sp_kernel(
    const u16* __restrict__ Qb, const u16* __restrict__ Kb,
    const u16* __restrict__ Vt, const u32* __restrict__ mbits,
    float* __restrict__ attn, u16* __restrict__ preWo)
{
  const int bh = blockIdx.y, qb = blockIdx.x;
  const int b = bh >> 4, h = bh & 15;
  const int q0 = qb * 128;
  const int tid = threadIdx.x, l = tid & 63, w = tid >> 6;
  __shared__ __attribute__((aligned(16))) char Ks2[32768];  // double-buffered K
  __shared__ __attribute__((aligned(16))) char Vsm[16384];
  __shared__ __attribute__((aligned(16))) char Psm[32768];  // Q staging, then P

  const char* Qrow = (const char*)(Qb + (size_t)bh * 131072ull);
  const char* Krow = (const char*)(Kb + (size_t)bh * 131072ull);
  const char* Vrow = (const char*)(Vt + (size_t)bh * 131072ull);

  // ---- stage Q into Psm (temp), extract fragments ----
#pragma unroll
  for (int j = 0; j < 4; ++j) {
    const int rt = w * 32 + j * 8 + (l >> 3);
    const int swk = ((l & 7) * 16) ^ ((rt & 7) << 4);
    GLDS16(Qrow + (size_t)(q0 + rt) * 128 + swk, Psm + (w * 32 + j * 8) * 128);
  }
  __syncthreads();
  short8 aq[2][2];
#pragma unroll
  for (int mf = 0; mf < 2; ++mf)
#pragma unroll
    for (int kk = 0; kk < 2; ++kk) {
      const int row = w * 32 + mf * 16 + (l & 15);
      const int kb = kk * 64 + (l >> 4) * 16;
      aq[mf][kk] = *(const short8*)(Psm + row * 128 + (kb ^ ((row & 7) << 4)));
    }
  // prologue: stage K(0) into buf0
#pragma unroll
  for (int j = 0; j < 4; ++j) {
    const int rt = w * 32 + j * 8 + (l >> 3);
    const int swk = ((l & 7) * 16) ^ ((rt & 7) << 4);
    GLDS16(Krow + (size_t)rt * 128 + swk, Ks2 + (w * 32 + j * 8) * 128);
  }
  __syncthreads();

  // ---- pass 1: per-lane online (m,l), no per-tile cross-lane work ----
  float m_l[2][4], l_l[2][4];
#pragma unroll
  for (int mf = 0; mf < 2; ++mf)
#pragma unroll
    for (int r = 0; r < 4; ++r) { m_l[mf][r] = -1e30f; l_l[mf][r] = 0.f; }

  for (int kt = 0; kt < 16; ++kt) {
    const char* kbuf = Ks2 + (kt & 1) * 16384;
    if (kt < 15) {
      char* nbuf = Ks2 + ((kt + 1) & 1) * 16384;
#pragma unroll
      for (int j = 0; j < 4; ++j) {
        const int rt = w * 32 + j * 8 + (l >> 3);
        const int swk = ((l & 7) * 16) ^ ((rt & 7) << 4);
        GLDS16(Krow + (size_t)((kt + 1) * 128 + rt) * 128 + swk, nbuf + (w * 32 + j * 8) * 128);
      }
    }
    f32x4 sc[2][8] = {};
#pragma unroll
    for (int kk = 0; kk < 2; ++kk) {
      short8 bkf[8];
#pragma unroll
      for (int fc = 0; fc < 8; ++fc) {
        const int row = fc * 16 + (l & 15);
        const int kb = kk * 64 + (l >> 4) * 16;
        bkf[fc] = *(const short8*)(kbuf + row * 128 + (kb ^ ((row & 7) << 4)));
      }
#pragma unroll
      for (int mf = 0; mf < 2; ++mf)
#pragma unroll
        for (int fc = 0; fc < 8; ++fc)
          sc[mf][fc] = __builtin_amdgcn_mfma_f32_16x16x32_bf16(aq[mf][kk], bkf[fc], sc[mf][fc], 0, 0, 0);
    }
#pragma unroll
    for (int mf = 0; mf < 2; ++mf) {
#pragma unroll
      for (int r = 0; r < 4; ++r) {
        const int qg = q0 + w * 32 + mf * 16 + (l >> 4) * 4 + r;
        const uint4 mk = *(const uint4*)(mbits + ((size_t)(b * 2048 + qg) * 64 + kt * 4));
        float vals[8];
#pragma unroll
        for (int fc = 0; fc < 8; ++fc) {
          const float sv = sc[mf][fc][r];
          const u32 mw = (fc < 2) ? mk.x : (fc < 4) ? mk.y : (fc < 6) ? mk.z : mk.w;
          const int sh = (l & 15) + ((fc & 1) << 4);
          vals[fc] = ((mw >> sh) & 1u) ? -1e30f : sv;
        }
        const float tm = fmaxf(fmaxf(fmaxf(vals[0], vals[1]), fmaxf(vals[2], vals[3])),
                               fmaxf(fmaxf(vals[4], vals[5]), fmaxf(vals[6], vals[7])));
        const float nm = fmaxf(m_l[mf][r], tm);
        float s = 0.f;
#pragma unroll
        for (int fc = 0; fc < 8; ++fc) s += EXP2(vals[fc] - nm);
        l_l[mf][r] = l_l[mf][r] * EXP2(m_l[mf][r] - nm) + s;
        m_l[mf][r] = nm;
      }
    }
    __syncthreads();
  }

  // pass-2 prologue staging (flies under the stat combine below)
#pragma unroll
  for (int j = 0; j < 4; ++j) {
    const int rt = w * 32 + j * 8 + (l >> 3);
    const int swk = ((l & 7) * 16) ^ ((rt & 7) << 4);
    GLDS16(Krow + (size_t)rt * 128 + swk, Ks2 + (w * 32 + j * 8) * 128);
  }
#pragma unroll
  for (int j = 0; j < 4; ++j) {
    const int rt = w * 16 + j * 4 + (l >> 4);
    const int swk = ((l & 15) * 16) ^ ((rt & 15) << 4);
    GLDS16(Vrow + (size_t)rt * 4096 + swk, Vsm + (w * 16 + j * 4) * 256);
  }

  // combine per-lane stats across the 16-lane row group
  float mrow[2][4], il[2][4];
#pragma unroll
  for (int mf = 0; mf < 2; ++mf)
#pragma unroll
    for (int r = 0; r < 4; ++r) {
      float m = m_l[mf][r], lv = l_l[mf][r];
#pragma unroll
      for (int d = 1; d < 16; d <<= 1) {
        const float mo = __shfl_xor(m, d);
        const float lo = __shfl_xor(lv, d);
        const float M = fmaxf(m, mo);
        lv = lv * EXP2(m - M) + lo * EXP2(mo - M);
        m = M;
      }
      mrow[mf][r] = m;
      il[mf][r] = 1.0f / lv;
    }
  __syncthreads();

  // ---- pass 2: attn write + PV ----
  f32x4 oacc[2][4] = {};
  for (int kt = 0; kt < 16; ++kt) {
    const char* kbuf = Ks2 + (kt & 1) * 16384;
    if (kt < 15) {
      char* nbuf = Ks2 + ((kt + 1) & 1) * 16384;
#pragma unroll
      for (int j = 0; j < 4; ++j) {
        const int rt = w * 32 + j * 8 + (l >> 3);
        const int swk = ((l & 7) * 16) ^ ((rt & 7) << 4);
        GLDS16(Krow + (size_t)((kt + 1) * 128 + rt) * 128 + swk, nbuf + (w * 32 + j * 8) * 128);
      }
    }
    f32x4 sc[2][8] = {};
#pragma unroll
    for (int kk = 0; kk < 2; ++kk) {
      short8 bkf[8];
#pragma unroll
      for (int fc = 0; fc < 8; ++fc) {
        const int row = fc * 16 + (l & 15);
        const int kb = kk * 64 + (l >> 4) * 16;
        bkf[fc] = *(const short8*)(kbuf + row * 128 + (kb ^ ((row & 7) << 4)));
      }
#pragma unroll
      for (int mf = 0; mf < 2; ++mf)
#pragma unroll
        for (int fc = 0; fc < 8; ++fc)
          sc[mf][fc] = __builtin_amdgcn_mfma_f32_16x16x32_bf16(aq[mf][kk], bkf[fc], sc[mf][fc], 0, 0, 0);
    }
    // exp + bf16 P into Psm (wave-private region)
#pragma unroll
    for (int mf = 0; mf < 2; ++mf) {
#pragma unroll
      for (int r = 0; r < 4; ++r) {
        const int qlocal = w * 32 + mf * 16 + (l >> 4) * 4 + r;
        const int qg = q0 + qlocal;
        const uint4 mk = *(const uint4*)(mbits + ((size_t)(b * 2048 + qg) * 64 + kt * 4));
#pragma unroll
        for (int fc = 0; fc < 8; ++fc) {
          float sv = sc[mf][fc][r];
          const u32 mw = (fc < 2) ? mk.x : (fc < 4) ? mk.y : (fc < 6) ? mk.z : mk.w;
          const int sh = (l & 15) + ((fc & 1) << 4);
          if ((mw >> sh) & 1u) sv = -1e30f;
          const float p = EXP2(sv - mrow[mf][r]) * il[mf][r];
          const int cb = (fc * 16 + (l & 15)) * 2;
          *(u16*)(Psm + qlocal * 256 + (cb ^ ((qlocal & 15) << 4))) = f2bf(p);
        }
      }
    }
    // coalesced attn store from Psm readback (drains under PV MFMA)
#pragma unroll
    for (int it = 0; it < 16; ++it) {
      const int rg = it & 7, kb2 = it >> 3;
      const int ql = w * 32 + rg * 4 + (l >> 4);
      const uint2 dv = *(const uint2*)(Psm + ql * 256 +
                        (((kb2 * 128 + (l & 15) * 8)) ^ ((ql & 15) << 4)));
      f32x4 o;
      o[0] = __uint_as_float(dv.x << 16);
      o[1] = __uint_as_float(dv.x & 0xffff0000u);
      o[2] = __uint_as_float(dv.y << 16);
      o[3] = __uint_as_float(dv.y & 0xffff0000u);
      __builtin_nontemporal_store(o, (f32x4*)(attn +
          ((size_t)bh * 2048 + q0 + ql) * 2048 + kt * 128 + kb2 * 64 + (l & 15) * 4));
    }
    __syncthreads();   // V(kt) + K(kt+1) ready; attn stores drained
    // PV
#pragma unroll
    for (int kk = 0; kk < 4; ++kk) {
      short8 pa[2], vb[4];
#pragma unroll
      for (int mf = 0; mf < 2; ++mf) {
        const int row = w * 32 + mf * 16 + (l & 15);
        const int kb = kk * 64 + (l >> 4) * 16;
        pa[mf] = *(const short8*)(Psm + row * 256 + (kb ^ ((row & 15) << 4)));
      }
#pragma unroll
      for (int fn = 0; fn < 4; ++fn) {
        const int row = fn * 16 + (l & 15);
        const int kb = kk * 64 + (l >> 4) * 16;
        vb[fn] = *(const short8*)(Vsm + row * 256 + (kb ^ ((row & 15) << 4)));
      }
#pragma unroll
      for (int mf = 0; mf < 2; ++mf)
#pragma unroll
        for (int fn = 0; fn < 4; ++fn)
          oacc[mf][fn] = __builtin_amdgcn_mfma_f32_16x16x32_bf16(pa[mf], vb[fn], oacc[mf][fn], 0, 0, 0);
    }
    __syncthreads();   // PV reads done -> Vsm free
    if (kt < 15) {
#pragma unroll
      for (int j = 0; j < 4; ++j) {
        const int rt = w * 16 + j * 4 + (l >> 4);
        const int swk = ((l & 15) * 16) ^ ((rt & 15) << 4);
        GLDS16(Vrow + (size_t)rt * 4096 + (kt + 1) * 256 + swk, Vsm + (w * 16 + j * 4) * 256);
      }
    }
  }

  // epilogue: scatter O into the reference's buggy-reshape layout (bf16)
#pragma unroll
  for (int mf = 0; mf < 2; ++mf)
#pragma unroll
    for (int fn = 0; fn < 4; ++fn)
#pragma unroll
      for (int r = 0; r < 4; ++r) {
        const int sg = q0 + w * 32 + mf * 16 + (l >> 4) * 4 + r;
        const int dd = fn * 16 + (l & 15);
        const size_t off = (size_t)b * 2097152ull +
                           ((size_t)((h >> 1) * 256 + (sg >> 3))) * 1024ull +
                           (size_t)((sg & 7) * 128 + (h & 1) * 64 + dd);
        preWo[off] = f2bf(oacc[mf][fn][r]);
      }
}

// ---------- output projection GEMM ----------
__global__ __launch_bounds__(256, 2) void gemm_out_kernel(
    const u16* __restrict__ A0, const u16* __restrict__ B0,
    const float* __restrict__ bias, float* __restrict__ out)
{
  const char* A = (const char*)A0;
  const char* B = (const char*)B0;
  const int m0 = blockIdx.y * 128, n0 = blockIdx.x * 128;
  const int tid = threadIdx.x, l = tid & 63, w = tid >> 6;
  const int wm = w >> 1, wn = w & 1;
  __shared__ __attribute__((aligned(16))) char SM[32768];
  char* Asm = SM;
  char* Bsm = SM + 16384;
  f32x4 acc[4][4] = {};
  for (int kt = 0; kt < 16; ++kt) {
#pragma unroll
    for (int j = 0; j < 4; ++j) {
      const int rt = w * 32 + j * 8 + (l >> 3);
      const int swk = ((l & 7) * 16) ^ ((rt & 7) << 4);
      GLDS16(A + (size_t)(m0 + rt) * 2048 + kt * 128 + swk, Asm + (w * 32 + j * 8) * 128);
      GLDS16(B + (size_t)(n0 + rt) * 2048 + kt * 128 + swk, Bsm + (w * 32 + j * 8) * 128);
    }
    __syncthreads();
#pragma unroll
    for (int kk = 0; kk < 2; ++kk) {
      short8 af[4], bfr[4];
#pragma unroll
      for (int mf = 0; mf < 4; ++mf) {
        const int row = wm * 64 + mf * 16 + (l & 15);
        const int kb = kk * 64 + (l >> 4) * 16;
        af[mf] = *(const short8*)(Asm + row * 128 + (kb ^ ((row & 7) << 4)));
      }
#pragma unroll
      for (int fc = 0; fc < 4; ++fc) {
        const int row = wn * 64 + fc * 16 + (l & 15);
        const int kb = kk * 64 + (l >> 4) * 16;
        bfr[fc] = *(const short8*)(Bsm + row * 128 + (kb ^ ((row & 7) << 4)));
      }
#pragma unroll
      for (int mf = 0; mf < 4; ++mf)
#pragma unroll
        for (int fc = 0; fc < 4; ++fc)
          acc[mf][fc] = __builtin_amdgcn_mfma_f32_16x16x32_bf16(af[mf], bfr[fc], acc[mf][fc], 0, 0, 0);
    }
    __syncthreads();
  }
#pragma unroll
  for (int mf = 0; mf < 4; ++mf)
#pragma unroll
    for (int fc = 0; fc < 4; ++fc)
#pragma unroll
      for (int r = 0; r < 4; ++r) {
        const int m = m0 + wm * 64 + mf * 16 + (l >> 4) * 4 + r;
        const int n = n0 + wn * 64 + fc * 16 + (l & 15);
        out[(size_t)m * 1024 + n] = acc[mf][fc][r] + bias[n];
      }
}

extern "C" void kernel_launch(void* const* d_in, const int* in_sizes, int n_in,
                              void* d_out, int out_size, void* d_ws, size_t ws_size,
                              hipStream_t stream) {
  const float* q  = (const float*)d_in[0];
  const float* k  = (const float*)d_in[1];
  const float* v  = (const float*)d_in[2];
  const int*  mask = (const int*)d_in[3];
  const float* Wq = (const float*)d_in[5];
  const float* bq = (const float*)d_in[6];
  const float* Wk = (const float*)d_in[7];
  const float* bk = (const float*)d_in[8];
  const float* Wv = (const float*)d_in[9];
  const float* bv = (const float*)d_in[10];
  const float* Wo = (const float*)d_in[11];
  const float* bo = (const float*)d_in[12];

  float* out0 = (float*)d_out;
  float* attn = out0 + 4194304;            // [32][2048][2048] fp32
  u16* X = (u16*)attn;                     // bf16 q,k,v copies live in the attn
                                           // region until attn_sp overwrites it
  char* ws = (char*)d_ws;
  u16* Qb    = (u16*)(ws);                 // [32][2048][64] bf16
  u16* Kb    = (u16*)(ws + 8388608);
  u16* Vt    = (u16*)(ws + 16777216);      // [32][64][2048] bf16
  u16* preWo = (u16*)(ws + 25165824);      // [4096][1024] bf16 (scrambled layout)
  u16* Wb    = (u16*)(ws + 33554432);      // Wq,Wk,Wv,Wo bf16
  u32* mbits = (u32*)(ws + 41943040);      // [2][2048][64] bit-packed mask

  prep_kernel<<<dim3(1024), 256, 0, stream>>>(q, k, v, mask, Wq, Wk, Wv, Wo,
                                              X, Wb, (u64*)mbits);
  gemm_qkv_kernel<<<dim3(8, 32, 3), 256, 0, stream>>>(X, Wb, bq, bk, bv, Qb, Kb, Vt);
  attn_sp_kernel<<<dim3(16, 32), 256, 0, stream>>>(Qb, Kb, Vt, mbits, attn, preWo);
  gemm_out_kernel<<<dim3(8, 32), 256, 0, stream>>>(preWo, Wb + 3u * 1048576u, bo, out0);
}